// Round 1
// baseline (991.366 us; speedup 1.0000x reference)
//
#include <hip/hip_runtime.h>

// ---------------------------------------------------------------------------
// GraphEncoder: 3x GCNConv(+ReLU, residual on 2/3) -> global_mean_pool ->
//               MLP (P1+ReLU, P2) -> LayerNorm
// Round 1: correctness-first fp32. CSR built per call (ws re-poisoned).
// ---------------------------------------------------------------------------

__global__ void count_kernel(const int* __restrict__ dst, int E, int* __restrict__ cnt) {
    int e = blockIdx.x * blockDim.x + threadIdx.x;
    if (e < E) atomicAdd(&cnt[dst[e]], 1);
}

__global__ void dinv_kernel(const int* __restrict__ cnt, float* __restrict__ dinv, int n) {
    int i = blockIdx.x * blockDim.x + threadIdx.x;
    if (i < n) dinv[i] = rsqrtf((float)cnt[i] + 1.0f);  // deg = in-degree + self loop
}

// Exclusive prefix sum over cnt[0..n) -> row_ptr[0..n]; single 1024-thread block.
__global__ void scan_kernel(const int* __restrict__ cnt, int n, int* __restrict__ row_ptr) {
    __shared__ int wsum[16];
    __shared__ int s_base;
    int tid = threadIdx.x;
    int lane = tid & 63;
    int w = tid >> 6;
    if (tid == 0) s_base = 0;
    __syncthreads();
    for (int start = 0; start < n; start += 1024) {
        int i = start + tid;
        int v = (i < n) ? cnt[i] : 0;
        int incl = v;
        #pragma unroll
        for (int off = 1; off < 64; off <<= 1) {
            int t = __shfl_up(incl, off);
            if (lane >= off) incl += t;
        }
        if (lane == 63) wsum[w] = incl;
        __syncthreads();
        int woff = 0;
        for (int j = 0; j < w; j++) woff += wsum[j];
        int excl = s_base + woff + incl - v;
        if (i < n) row_ptr[i] = excl;
        __syncthreads();
        if (tid == 1023) s_base = excl + v;
        __syncthreads();
    }
    if (threadIdx.x == 0) row_ptr[n] = s_base;
}

__global__ void scatter_kernel(const int* __restrict__ src, const int* __restrict__ dst, int E,
                               const int* __restrict__ row_ptr, int* __restrict__ fill,
                               const float* __restrict__ dinv, int* __restrict__ csr_src,
                               float* __restrict__ csr_coef) {
    int e = blockIdx.x * blockDim.x + threadIdx.x;
    if (e < E) {
        int d = dst[e], s = src[e];
        int pos = atomicAdd(&fill[d], 1);
        int idx = row_ptr[d] + pos;
        csr_src[idx] = s;
        csr_coef[idx] = dinv[s] * dinv[d];
    }
}

// C[M,N] = A[M,K] @ B[K,N] (+bias) (+relu). 128x128 tile, BK=16, 8x8/thread.
__launch_bounds__(256)
__global__ void gemm_kernel(const float* __restrict__ A, const float* __restrict__ B,
                            const float* __restrict__ bias, float* __restrict__ C,
                            int M, int N, int K, int relu) {
    __shared__ float As[16][128];
    __shared__ float Bs[16][128];
    int tid = threadIdx.x;
    int tx = tid & 15, ty = tid >> 4;
    int bm = blockIdx.y * 128, bn = blockIdx.x * 128;

    float acc[8][8];
    #pragma unroll
    for (int i = 0; i < 8; i++)
        #pragma unroll
        for (int j = 0; j < 8; j++) acc[i][j] = 0.f;

    for (int kt = 0; kt < K; kt += 16) {
        #pragma unroll
        for (int t = 0; t < 2; t++) {
            int f = tid * 2 + t;       // 0..511  (128 rows x 4 float4)
            int m = f >> 2;
            int kq = f & 3;
            int row = bm + m;
            float4 av = make_float4(0.f, 0.f, 0.f, 0.f);
            if (row < M) av = *(const float4*)(A + (size_t)row * K + kt + kq * 4);
            As[kq * 4 + 0][m] = av.x;
            As[kq * 4 + 1][m] = av.y;
            As[kq * 4 + 2][m] = av.z;
            As[kq * 4 + 3][m] = av.w;
        }
        #pragma unroll
        for (int t = 0; t < 2; t++) {
            int f = tid * 2 + t;       // 0..511  (16 rows x 32 float4)
            int k = f >> 5;
            int nq = f & 31;
            float4 bv = *(const float4*)(B + (size_t)(kt + k) * N + bn + nq * 4);
            *(float4*)&Bs[k][nq * 4] = bv;
        }
        __syncthreads();
        #pragma unroll
        for (int kk = 0; kk < 16; kk++) {
            float a[8], b[8];
            *(float4*)&a[0] = *(const float4*)&As[kk][ty * 8];
            *(float4*)&a[4] = *(const float4*)&As[kk][ty * 8 + 4];
            *(float4*)&b[0] = *(const float4*)&Bs[kk][tx * 8];
            *(float4*)&b[4] = *(const float4*)&Bs[kk][tx * 8 + 4];
            #pragma unroll
            for (int i = 0; i < 8; i++)
                #pragma unroll
                for (int j = 0; j < 8; j++) acc[i][j] += a[i] * b[j];
        }
        __syncthreads();
    }

    #pragma unroll
    for (int i = 0; i < 8; i++) {
        int row = bm + ty * 8 + i;
        if (row < M) {
            float o[8];
            #pragma unroll
            for (int j = 0; j < 8; j++) {
                float v = acc[i][j];
                if (bias) v += bias[bn + tx * 8 + j];
                if (relu) v = fmaxf(v, 0.f);
                o[j] = v;
            }
            *(float4*)(C + (size_t)row * N + bn + tx * 8) = *(float4*)&o[0];
            *(float4*)(C + (size_t)row * N + bn + tx * 8 + 4) = *(float4*)&o[4];
        }
    }
}

// One wave per dst node; lane covers 4 contiguous cols (H=256 = 64 lanes * 4).
// out = relu(sum_e coef*hw[src] + dinv^2*hw[node] + bias) (+ residual)
__launch_bounds__(256)
__global__ void aggregate_kernel(const float* __restrict__ hw, const int* __restrict__ row_ptr,
                                 const int* __restrict__ csr_src, const float* __restrict__ csr_coef,
                                 const float* __restrict__ dinv, const float* __restrict__ bias,
                                 const float* __restrict__ residual, float* __restrict__ out, int n) {
    int node = blockIdx.x * 4 + (threadIdx.x >> 6);
    int lane = threadIdx.x & 63;
    if (node >= n) return;
    float di = dinv[node];
    float self = di * di;
    float4 acc = *(const float4*)(hw + (size_t)node * 256 + lane * 4);
    acc.x *= self; acc.y *= self; acc.z *= self; acc.w *= self;
    int beg = row_ptr[node], end = row_ptr[node + 1];
    for (int k = beg; k < end; k++) {
        int s = csr_src[k];
        float c = csr_coef[k];
        float4 v = *(const float4*)(hw + (size_t)s * 256 + lane * 4);
        acc.x += c * v.x; acc.y += c * v.y; acc.z += c * v.z; acc.w += c * v.w;
    }
    float4 bv = *(const float4*)(bias + lane * 4);
    acc.x += bv.x; acc.y += bv.y; acc.z += bv.z; acc.w += bv.w;
    acc.x = fmaxf(acc.x, 0.f); acc.y = fmaxf(acc.y, 0.f);
    acc.z = fmaxf(acc.z, 0.f); acc.w = fmaxf(acc.w, 0.f);
    if (residual) {
        float4 r = *(const float4*)(residual + (size_t)node * 256 + lane * 4);
        acc.x += r.x; acc.y += r.y; acc.z += r.z; acc.w += r.w;
    }
    *(float4*)(out + (size_t)node * 256 + lane * 4) = acc;
}

// One 256-thread block per graph; batch is sorted -> contiguous node range.
__global__ void pool_kernel(const float* __restrict__ h, const int* __restrict__ batch,
                            float* __restrict__ g0, int n) {
    int g = blockIdx.x;
    __shared__ int s_lo, s_hi;
    if (threadIdx.x == 0) {
        int lo = 0, hi = n;
        while (lo < hi) { int mid = (lo + hi) >> 1; if (batch[mid] < g) lo = mid + 1; else hi = mid; }
        s_lo = lo;
        int lo2 = lo, hi2 = n;
        while (lo2 < hi2) { int mid = (lo2 + hi2) >> 1; if (batch[mid] < g + 1) lo2 = mid + 1; else hi2 = mid; }
        s_hi = lo2;
    }
    __syncthreads();
    int lo = s_lo, hi = s_hi;
    float acc = 0.f;
    for (int i = lo; i < hi; i++) acc += h[(size_t)i * 256 + threadIdx.x];
    float cntf = (float)(hi - lo);
    g0[(size_t)g * 256 + threadIdx.x] = acc / fmaxf(cntf, 1.0f);
}

// One wave per row of 768; 4 rows per block.
__launch_bounds__(256)
__global__ void ln_kernel(const float* __restrict__ g2, const float* __restrict__ gamma,
                          const float* __restrict__ beta, float* __restrict__ out, int rows) {
    int row = blockIdx.x * 4 + (threadIdx.x >> 6);
    int lane = threadIdx.x & 63;
    if (row >= rows) return;
    const float* r = g2 + (size_t)row * 768;
    float v[12];
    float s = 0.f, s2 = 0.f;
    #pragma unroll
    for (int j = 0; j < 12; j++) {
        v[j] = r[lane + 64 * j];
        s += v[j];
        s2 += v[j] * v[j];
    }
    #pragma unroll
    for (int off = 32; off > 0; off >>= 1) {
        s += __shfl_down(s, off);
        s2 += __shfl_down(s2, off);
    }
    s = __shfl(s, 0);
    s2 = __shfl(s2, 0);
    float mu = s * (1.0f / 768.0f);
    float var = s2 * (1.0f / 768.0f) - mu * mu;
    float inv = rsqrtf(var + 1e-5f);
    #pragma unroll
    for (int j = 0; j < 12; j++) {
        int c = lane + 64 * j;
        out[(size_t)row * 768 + c] = (v[j] - mu) * inv * gamma[c] + beta[c];
    }
}

extern "C" void kernel_launch(void* const* d_in, const int* in_sizes, int n_in,
                              void* d_out, int out_size, void* d_ws, size_t ws_size,
                              hipStream_t stream) {
    const float* x    = (const float*)d_in[0];
    const int* eidx   = (const int*)d_in[1];
    const int* batch  = (const int*)d_in[2];
    const float* W1   = (const float*)d_in[3];
    const float* b1   = (const float*)d_in[4];
    const float* W2   = (const float*)d_in[5];
    const float* b2   = (const float*)d_in[6];
    const float* W3   = (const float*)d_in[7];
    const float* b3   = (const float*)d_in[8];
    const float* P1   = (const float*)d_in[9];
    const float* pb1  = (const float*)d_in[10];
    const float* P2   = (const float*)d_in[11];
    const float* pb2  = (const float*)d_in[12];
    const float* ln_g = (const float*)d_in[13];
    const float* ln_b = (const float*)d_in[14];
    float* out = (float*)d_out;

    const int N = in_sizes[2];            // 50000
    const int E = in_sizes[1] / 2;        // 800000
    const int F_IN = in_sizes[0] / N;     // 128
    const int H = in_sizes[4];            // 256
    const int D = in_sizes[12];           // 768
    const int G = out_size / D;           // 1024
    const int NPAD = (N + 127) & ~127;    // padded node count for ws layout

    const int* src = eidx;
    const int* dst = eidx + E;

    char* ws = (char*)d_ws;
    size_t off = 0;
    auto alloc = [&](size_t bytes) -> char* {
        char* p = ws + off;
        off = (off + bytes + 255) & ~(size_t)255;
        return p;
    };
    int*   cnt      = (int*)alloc((size_t)NPAD * 4);   // cnt & fill contiguous -> one memset
    int*   fill     = (int*)alloc((size_t)NPAD * 4);
    float* dinv     = (float*)alloc((size_t)NPAD * 4);
    int*   row_ptr  = (int*)alloc((size_t)(N + 1) * 4);
    int*   csr_src  = (int*)alloc((size_t)E * 4);
    float* csr_coef = (float*)alloc((size_t)E * 4);
    float* hw       = (float*)alloc((size_t)N * H * 4);
    float* hA       = (float*)alloc((size_t)N * H * 4);
    float* hB       = (float*)alloc((size_t)N * H * 4);
    float* g0       = (float*)alloc((size_t)G * H * 4);
    float* g1       = (float*)alloc((size_t)G * H * 4);
    float* g2       = (float*)alloc((size_t)G * D * 4);
    (void)ws_size; (void)n_in;

    // --- CSR build -----------------------------------------------------------
    hipMemsetAsync(cnt, 0, (size_t)2 * NPAD * 4, stream);
    count_kernel<<<(E + 255) / 256, 256, 0, stream>>>(dst, E, cnt);
    dinv_kernel<<<(N + 255) / 256, 256, 0, stream>>>(cnt, dinv, N);
    scan_kernel<<<1, 1024, 0, stream>>>(cnt, N, row_ptr);
    scatter_kernel<<<(E + 255) / 256, 256, 0, stream>>>(src, dst, E, row_ptr, fill, dinv,
                                                        csr_src, csr_coef);

    // --- GCN layers ----------------------------------------------------------
    dim3 gemm_grid(H / 128, (N + 127) / 128);
    int agg_grid = (N + 3) / 4;

    gemm_kernel<<<gemm_grid, 256, 0, stream>>>(x, W1, nullptr, hw, N, H, F_IN, 0);
    aggregate_kernel<<<agg_grid, 256, 0, stream>>>(hw, row_ptr, csr_src, csr_coef, dinv,
                                                   b1, nullptr, hA, N);   // h1

    gemm_kernel<<<gemm_grid, 256, 0, stream>>>(hA, W2, nullptr, hw, N, H, H, 0);
    aggregate_kernel<<<agg_grid, 256, 0, stream>>>(hw, row_ptr, csr_src, csr_coef, dinv,
                                                   b2, hA, hB, N);        // h2 = relu+h1

    gemm_kernel<<<gemm_grid, 256, 0, stream>>>(hB, W3, nullptr, hw, N, H, H, 0);
    aggregate_kernel<<<agg_grid, 256, 0, stream>>>(hw, row_ptr, csr_src, csr_coef, dinv,
                                                   b3, hB, hA, N);        // h3 = relu+h2 (reuse hA)

    // --- pool + MLP + LN -----------------------------------------------------
    pool_kernel<<<G, 256, 0, stream>>>(hA, batch, g0, N);
    dim3 p1_grid(H / 128, (G + 127) / 128);
    gemm_kernel<<<p1_grid, 256, 0, stream>>>(g0, P1, pb1, g1, G, H, H, 1);
    dim3 p2_grid(D / 128, (G + 127) / 128);
    gemm_kernel<<<p2_grid, 256, 0, stream>>>(g1, P2, pb2, g2, G, D, H, 0);
    ln_kernel<<<G / 4, 256, 0, stream>>>(g2, ln_g, ln_b, out, G);
}

// Round 2
// 716.375 us; speedup vs baseline: 1.3839x; 1.3839x over previous
//
#include <hip/hip_runtime.h>

// ---------------------------------------------------------------------------
// GraphEncoder round 2: bf16 MFMA GEMMs + bf16 gather aggregation.
// h tensors (hw/hA/hB) are bf16 end-to-end; accumulation in fp32.
// MLP (1024-row GEMMs) + LN stay fp32.
// ---------------------------------------------------------------------------

typedef __attribute__((ext_vector_type(8))) short short8;
typedef __attribute__((ext_vector_type(4))) float f32x4;

__device__ __forceinline__ float bf2f(unsigned short s) {
    union { unsigned u; float f; } v;
    v.u = ((unsigned)s) << 16;
    return v.f;
}
__device__ __forceinline__ unsigned short f2bf(float f) {
    union { float f; unsigned u; } v;
    v.f = f;
    unsigned r = (v.u + 0x7FFFu + ((v.u >> 16) & 1u)) >> 16;
    return (unsigned short)r;
}

// ---------------------------- CSR build ------------------------------------

__global__ void count_kernel(const int* __restrict__ dst, int E, int* __restrict__ cnt) {
    int e = blockIdx.x * blockDim.x + threadIdx.x;
    if (e < E) atomicAdd(&cnt[dst[e]], 1);
}

__global__ void dinv_kernel(const int* __restrict__ cnt, float* __restrict__ dinv, int n) {
    int i = blockIdx.x * blockDim.x + threadIdx.x;
    if (i < n) dinv[i] = rsqrtf((float)cnt[i] + 1.0f);  // deg = in-degree + self loop
}

__global__ void scan_kernel(const int* __restrict__ cnt, int n, int* __restrict__ row_ptr) {
    __shared__ int wsum[16];
    __shared__ int s_base;
    int tid = threadIdx.x;
    int lane = tid & 63;
    int w = tid >> 6;
    if (tid == 0) s_base = 0;
    __syncthreads();
    for (int start = 0; start < n; start += 1024) {
        int i = start + tid;
        int v = (i < n) ? cnt[i] : 0;
        int incl = v;
        #pragma unroll
        for (int off = 1; off < 64; off <<= 1) {
            int t = __shfl_up(incl, off);
            if (lane >= off) incl += t;
        }
        if (lane == 63) wsum[w] = incl;
        __syncthreads();
        int woff = 0;
        for (int j = 0; j < w; j++) woff += wsum[j];
        int excl = s_base + woff + incl - v;
        if (i < n) row_ptr[i] = excl;
        __syncthreads();
        if (tid == 1023) s_base = excl + v;
        __syncthreads();
    }
    if (threadIdx.x == 0) row_ptr[n] = s_base;
}

__global__ void scatter_kernel(const int* __restrict__ src, const int* __restrict__ dst, int E,
                               const int* __restrict__ row_ptr, int* __restrict__ fill,
                               const float* __restrict__ dinv, int* __restrict__ csr_src,
                               float* __restrict__ csr_coef) {
    int e = blockIdx.x * blockDim.x + threadIdx.x;
    if (e < E) {
        int d = dst[e], s = src[e];
        int pos = atomicAdd(&fill[d], 1);
        int idx = row_ptr[d] + pos;
        csr_src[idx] = s;
        csr_coef[idx] = dinv[s] * dinv[d];
    }
}

// ---------------------------- conversions ----------------------------------

__global__ void convert_bf16_vec(const float* __restrict__ in, unsigned short* __restrict__ out, int n4) {
    int i = blockIdx.x * blockDim.x + threadIdx.x;
    if (i < n4) {
        float4 v = ((const float4*)in)[i];
        ushort4 o;
        o.x = f2bf(v.x); o.y = f2bf(v.y); o.z = f2bf(v.z); o.w = f2bf(v.w);
        ((ushort4*)out)[i] = o;
    }
}

// W [K,N] fp32 -> Wt [N,K] bf16
__global__ void convert_wt(const float* __restrict__ W, unsigned short* __restrict__ Wt, int K, int N) {
    int idx = blockIdx.x * blockDim.x + threadIdx.x;
    if (idx < K * N) {
        int k = idx / N, n = idx - k * N;
        Wt[(size_t)n * K + k] = f2bf(W[idx]);
    }
}

// ---------------------------- bf16 MFMA GEMM -------------------------------
// C[M,N] = A[M,K] @ Bt[N,K]^T, all bf16, fp32 accumulate, bf16 out.
// 128x128 tile, BK=32, 4 waves in 2x2; each wave 64x64 via 4x4 16x16x32 frags.
#define LDA 40  // padded LDS row stride in shorts (32 + 8)

__launch_bounds__(256)
__global__ void mfma_gemm(const unsigned short* __restrict__ A,
                          const unsigned short* __restrict__ Bt,
                          unsigned short* __restrict__ C,
                          int M, int N, int K) {
    __shared__ unsigned short As[128 * LDA];
    __shared__ unsigned short Bs[128 * LDA];
    int tid = threadIdx.x;
    int wave = tid >> 6, lane = tid & 63;
    int wm = wave >> 1, wn = wave & 1;
    int q = lane >> 4, r = lane & 15;
    int bm = blockIdx.y * 128, bn = blockIdx.x * 128;

    f32x4 acc[4][4];
    #pragma unroll
    for (int i = 0; i < 4; i++)
        #pragma unroll
        for (int j = 0; j < 4; j++) acc[i][j] = (f32x4){0.f, 0.f, 0.f, 0.f};

    for (int kt = 0; kt < K; kt += 32) {
        #pragma unroll
        for (int c = 0; c < 2; c++) {
            int f = tid * 2 + c;          // 0..511: 128 rows x 4 chunks of 8 shorts
            int row = f >> 2, kq = f & 3;
            int grow = bm + row;
            short8 va = {0, 0, 0, 0, 0, 0, 0, 0};
            if (grow < M) va = *(const short8*)(A + (size_t)grow * K + kt + kq * 8);
            *(short8*)&As[row * LDA + kq * 8] = va;
            int nrow = bn + row;
            short8 vb = {0, 0, 0, 0, 0, 0, 0, 0};
            if (nrow < N) vb = *(const short8*)(Bt + (size_t)nrow * K + kt + kq * 8);
            *(short8*)&Bs[row * LDA + kq * 8] = vb;
        }
        __syncthreads();
        short8 af[4], bf[4];
        #pragma unroll
        for (int i = 0; i < 4; i++)
            af[i] = *(short8*)&As[(wm * 64 + i * 16 + r) * LDA + q * 8];
        #pragma unroll
        for (int j = 0; j < 4; j++)
            bf[j] = *(short8*)&Bs[(wn * 64 + j * 16 + r) * LDA + q * 8];
        #pragma unroll
        for (int i = 0; i < 4; i++)
            #pragma unroll
            for (int j = 0; j < 4; j++)
                acc[i][j] = __builtin_amdgcn_mfma_f32_16x16x32_bf16(af[i], bf[j], acc[i][j], 0, 0, 0);
        __syncthreads();
    }

    #pragma unroll
    for (int i = 0; i < 4; i++) {
        #pragma unroll
        for (int p = 0; p < 4; p++) {
            int row = bm + wm * 64 + i * 16 + q * 4 + p;
            if (row < M) {
                #pragma unroll
                for (int j = 0; j < 4; j++) {
                    int col = bn + wn * 64 + j * 16 + r;
                    C[(size_t)row * N + col] = f2bf(acc[i][j][p]);
                }
            }
        }
    }
}

// ---------------------------- aggregation (bf16) ---------------------------
// One wave per dst node; lane covers 4 cols (H=256 = 64*4).
// out = relu(sum coef*hw[src] + dinv^2*hw[node] + bias) (+ residual), bf16 io.
__launch_bounds__(256)
__global__ void aggregate_kernel(const unsigned short* __restrict__ hw,
                                 const int* __restrict__ row_ptr,
                                 const int* __restrict__ csr_src,
                                 const float* __restrict__ csr_coef,
                                 const float* __restrict__ dinv,
                                 const float* __restrict__ bias,
                                 const unsigned short* __restrict__ residual,
                                 unsigned short* __restrict__ out, int n) {
    int node = blockIdx.x * 4 + (threadIdx.x >> 6);
    int lane = threadIdx.x & 63;
    if (node >= n) return;
    float di = dinv[node];
    float self = di * di;
    ushort4 sv = *(const ushort4*)(hw + (size_t)node * 256 + lane * 4);
    float ax = self * bf2f(sv.x), ay = self * bf2f(sv.y);
    float az = self * bf2f(sv.z), aw = self * bf2f(sv.w);
    int beg = row_ptr[node], end = row_ptr[node + 1];
    for (int k = beg; k < end; k++) {
        int s = csr_src[k];
        float c = csr_coef[k];
        ushort4 v = *(const ushort4*)(hw + (size_t)s * 256 + lane * 4);
        ax += c * bf2f(v.x); ay += c * bf2f(v.y);
        az += c * bf2f(v.z); aw += c * bf2f(v.w);
    }
    float4 bv = *(const float4*)(bias + lane * 4);
    ax = fmaxf(ax + bv.x, 0.f); ay = fmaxf(ay + bv.y, 0.f);
    az = fmaxf(az + bv.z, 0.f); aw = fmaxf(aw + bv.w, 0.f);
    if (residual) {
        ushort4 rv = *(const ushort4*)(residual + (size_t)node * 256 + lane * 4);
        ax += bf2f(rv.x); ay += bf2f(rv.y); az += bf2f(rv.z); aw += bf2f(rv.w);
    }
    ushort4 o;
    o.x = f2bf(ax); o.y = f2bf(ay); o.z = f2bf(az); o.w = f2bf(aw);
    *(ushort4*)(out + (size_t)node * 256 + lane * 4) = o;
}

// ---------------------------- pool / MLP / LN ------------------------------

__global__ void pool_kernel(const unsigned short* __restrict__ h, const int* __restrict__ batch,
                            float* __restrict__ g0, int n) {
    int g = blockIdx.x;
    __shared__ int s_lo, s_hi;
    if (threadIdx.x == 0) {
        int lo = 0, hi = n;
        while (lo < hi) { int mid = (lo + hi) >> 1; if (batch[mid] < g) lo = mid + 1; else hi = mid; }
        s_lo = lo;
        int lo2 = lo, hi2 = n;
        while (lo2 < hi2) { int mid = (lo2 + hi2) >> 1; if (batch[mid] < g + 1) lo2 = mid + 1; else hi2 = mid; }
        s_hi = lo2;
    }
    __syncthreads();
    int lo = s_lo, hi = s_hi;
    float acc = 0.f;
    for (int i = lo; i < hi; i++) acc += bf2f(h[(size_t)i * 256 + threadIdx.x]);
    float cntf = (float)(hi - lo);
    g0[(size_t)g * 256 + threadIdx.x] = acc / fmaxf(cntf, 1.0f);
}

// fp32 tiled GEMM for the small MLP (M=1024).
__launch_bounds__(256)
__global__ void gemm_kernel(const float* __restrict__ A, const float* __restrict__ B,
                            const float* __restrict__ bias, float* __restrict__ C,
                            int M, int N, int K, int relu) {
    __shared__ float As[16][128];
    __shared__ float Bs[16][128];
    int tid = threadIdx.x;
    int tx = tid & 15, ty = tid >> 4;
    int bm = blockIdx.y * 128, bn = blockIdx.x * 128;

    float acc[8][8];
    #pragma unroll
    for (int i = 0; i < 8; i++)
        #pragma unroll
        for (int j = 0; j < 8; j++) acc[i][j] = 0.f;

    for (int kt = 0; kt < K; kt += 16) {
        #pragma unroll
        for (int t = 0; t < 2; t++) {
            int f = tid * 2 + t;
            int m = f >> 2;
            int kq = f & 3;
            int row = bm + m;
            float4 av = make_float4(0.f, 0.f, 0.f, 0.f);
            if (row < M) av = *(const float4*)(A + (size_t)row * K + kt + kq * 4);
            As[kq * 4 + 0][m] = av.x;
            As[kq * 4 + 1][m] = av.y;
            As[kq * 4 + 2][m] = av.z;
            As[kq * 4 + 3][m] = av.w;
        }
        #pragma unroll
        for (int t = 0; t < 2; t++) {
            int f = tid * 2 + t;
            int k = f >> 5;
            int nq = f & 31;
            float4 bv = *(const float4*)(B + (size_t)(kt + k) * N + bn + nq * 4);
            *(float4*)&Bs[k][nq * 4] = bv;
        }
        __syncthreads();
        #pragma unroll
        for (int kk = 0; kk < 16; kk++) {
            float a[8], b[8];
            *(float4*)&a[0] = *(const float4*)&As[kk][ty * 8];
            *(float4*)&a[4] = *(const float4*)&As[kk][ty * 8 + 4];
            *(float4*)&b[0] = *(const float4*)&Bs[kk][tx * 8];
            *(float4*)&b[4] = *(const float4*)&Bs[kk][tx * 8 + 4];
            #pragma unroll
            for (int i = 0; i < 8; i++)
                #pragma unroll
                for (int j = 0; j < 8; j++) acc[i][j] += a[i] * b[j];
        }
        __syncthreads();
    }

    #pragma unroll
    for (int i = 0; i < 8; i++) {
        int row = bm + ty * 8 + i;
        if (row < M) {
            float o[8];
            #pragma unroll
            for (int j = 0; j < 8; j++) {
                float v = acc[i][j];
                if (bias) v += bias[bn + tx * 8 + j];
                if (relu) v = fmaxf(v, 0.f);
                o[j] = v;
            }
            *(float4*)(C + (size_t)row * N + bn + tx * 8) = *(float4*)&o[0];
            *(float4*)(C + (size_t)row * N + bn + tx * 8 + 4) = *(float4*)&o[4];
        }
    }
}

__launch_bounds__(256)
__global__ void ln_kernel(const float* __restrict__ g2, const float* __restrict__ gamma,
                          const float* __restrict__ beta, float* __restrict__ out, int rows) {
    int row = blockIdx.x * 4 + (threadIdx.x >> 6);
    int lane = threadIdx.x & 63;
    if (row >= rows) return;
    const float* r = g2 + (size_t)row * 768;
    float v[12];
    float s = 0.f, s2 = 0.f;
    #pragma unroll
    for (int j = 0; j < 12; j++) {
        v[j] = r[lane + 64 * j];
        s += v[j];
        s2 += v[j] * v[j];
    }
    #pragma unroll
    for (int off = 32; off > 0; off >>= 1) {
        s += __shfl_down(s, off);
        s2 += __shfl_down(s2, off);
    }
    s = __shfl(s, 0);
    s2 = __shfl(s2, 0);
    float mu = s * (1.0f / 768.0f);
    float var = s2 * (1.0f / 768.0f) - mu * mu;
    float inv = rsqrtf(var + 1e-5f);
    #pragma unroll
    for (int j = 0; j < 12; j++) {
        int c = lane + 64 * j;
        out[(size_t)row * 768 + c] = (v[j] - mu) * inv * gamma[c] + beta[c];
    }
}

// ---------------------------------------------------------------------------

extern "C" void kernel_launch(void* const* d_in, const int* in_sizes, int n_in,
                              void* d_out, int out_size, void* d_ws, size_t ws_size,
                              hipStream_t stream) {
    const float* x    = (const float*)d_in[0];
    const int* eidx   = (const int*)d_in[1];
    const int* batch  = (const int*)d_in[2];
    const float* W1   = (const float*)d_in[3];
    const float* b1   = (const float*)d_in[4];
    const float* W2   = (const float*)d_in[5];
    const float* b2   = (const float*)d_in[6];
    const float* W3   = (const float*)d_in[7];
    const float* b3   = (const float*)d_in[8];
    const float* P1   = (const float*)d_in[9];
    const float* pb1  = (const float*)d_in[10];
    const float* P2   = (const float*)d_in[11];
    const float* pb2  = (const float*)d_in[12];
    const float* ln_g = (const float*)d_in[13];
    const float* ln_b = (const float*)d_in[14];
    float* out = (float*)d_out;

    const int N = in_sizes[2];            // 50000
    const int E = in_sizes[1] / 2;        // 800000
    const int F_IN = in_sizes[0] / N;     // 128
    const int H = in_sizes[4];            // 256
    const int D = in_sizes[12];           // 768
    const int G = out_size / D;           // 1024
    const int NPAD = (N + 127) & ~127;

    const int* src = eidx;
    const int* dst = eidx + E;

    char* ws = (char*)d_ws;
    size_t off = 0;
    auto alloc = [&](size_t bytes) -> char* {
        char* p = ws + off;
        off = (off + bytes + 255) & ~(size_t)255;
        return p;
    };
    int*   cnt      = (int*)alloc((size_t)NPAD * 4);   // cnt & fill contiguous -> one memset
    int*   fill     = (int*)alloc((size_t)NPAD * 4);
    float* dinv     = (float*)alloc((size_t)NPAD * 4);
    int*   row_ptr  = (int*)alloc((size_t)(N + 1) * 4);
    int*   csr_src  = (int*)alloc((size_t)E * 4);
    float* csr_coef = (float*)alloc((size_t)E * 4);
    unsigned short* x_bf = (unsigned short*)alloc((size_t)N * F_IN * 2);
    unsigned short* Wt1  = (unsigned short*)alloc((size_t)F_IN * H * 2);
    unsigned short* Wt2  = (unsigned short*)alloc((size_t)H * H * 2);
    unsigned short* Wt3  = (unsigned short*)alloc((size_t)H * H * 2);
    unsigned short* hw   = (unsigned short*)alloc((size_t)N * H * 2);
    unsigned short* hA   = (unsigned short*)alloc((size_t)N * H * 2);
    unsigned short* hB   = (unsigned short*)alloc((size_t)N * H * 2);
    float* g0 = (float*)alloc((size_t)G * H * 4);
    float* g1 = (float*)alloc((size_t)G * H * 4);
    float* g2 = (float*)alloc((size_t)G * D * 4);
    (void)ws_size; (void)n_in;

    // --- CSR build -----------------------------------------------------------
    hipMemsetAsync(cnt, 0, (size_t)2 * NPAD * 4, stream);
    count_kernel<<<(E + 255) / 256, 256, 0, stream>>>(dst, E, cnt);
    dinv_kernel<<<(N + 255) / 256, 256, 0, stream>>>(cnt, dinv, N);
    scan_kernel<<<1, 1024, 0, stream>>>(cnt, N, row_ptr);
    scatter_kernel<<<(E + 255) / 256, 256, 0, stream>>>(src, dst, E, row_ptr, fill, dinv,
                                                        csr_src, csr_coef);

    // --- conversions ---------------------------------------------------------
    convert_bf16_vec<<<(N * F_IN / 4 + 255) / 256, 256, 0, stream>>>(x, x_bf, N * F_IN / 4);
    convert_wt<<<(F_IN * H + 255) / 256, 256, 0, stream>>>(W1, Wt1, F_IN, H);
    convert_wt<<<(H * H + 255) / 256, 256, 0, stream>>>(W2, Wt2, H, H);
    convert_wt<<<(H * H + 255) / 256, 256, 0, stream>>>(W3, Wt3, H, H);

    // --- GCN layers ----------------------------------------------------------
    dim3 ggrid(H / 128, (N + 127) / 128);
    int agg_grid = (N + 3) / 4;

    mfma_gemm<<<ggrid, 256, 0, stream>>>(x_bf, Wt1, hw, N, H, F_IN);
    aggregate_kernel<<<agg_grid, 256, 0, stream>>>(hw, row_ptr, csr_src, csr_coef, dinv,
                                                   b1, nullptr, hA, N);   // h1

    mfma_gemm<<<ggrid, 256, 0, stream>>>(hA, Wt2, hw, N, H, H);
    aggregate_kernel<<<agg_grid, 256, 0, stream>>>(hw, row_ptr, csr_src, csr_coef, dinv,
                                                   b2, hA, hB, N);        // h2 = relu(.)+h1

    mfma_gemm<<<ggrid, 256, 0, stream>>>(hB, Wt3, hw, N, H, H);
    aggregate_kernel<<<agg_grid, 256, 0, stream>>>(hw, row_ptr, csr_src, csr_coef, dinv,
                                                   b3, hB, hA, N);        // h3 = relu(.)+h2

    // --- pool + MLP + LN -----------------------------------------------------
    pool_kernel<<<G, 256, 0, stream>>>(hA, batch, g0, N);
    dim3 p1_grid(H / 128, (G + 127) / 128);
    gemm_kernel<<<p1_grid, 256, 0, stream>>>(g0, P1, pb1, g1, G, H, H, 1);
    dim3 p2_grid(D / 128, (G + 127) / 128);
    gemm_kernel<<<p2_grid, 256, 0, stream>>>(g1, P2, pb2, g2, G, D, H, 0);
    ln_kernel<<<G / 4, 256, 0, stream>>>(g2, ln_g, ln_b, out, G);
}

// Round 3
// 678.590 us; speedup vs baseline: 1.4609x; 1.0557x over previous
//
#include <hip/hip_runtime.h>

// ---------------------------------------------------------------------------
// GraphEncoder round 3:
//  - aggregate-FIRST per layer:  h_l = relu((Â h_{l-1} + dinv^2 h_{l-1}) W + b) [+ res]
//    -> layer-1 gather runs in 128-dim input space (half traffic)
//    -> bias/relu/residual fused into MFMA-GEMM epilogue
//  - aggregator: lane-parallel edge prefetch + __shfl broadcast + 4x unroll
//    so gathers are independent (memory-level parallelism, not dependent chain)
// ---------------------------------------------------------------------------

typedef __attribute__((ext_vector_type(8))) short short8;
typedef __attribute__((ext_vector_type(4))) float f32x4;

__device__ __forceinline__ float bf2f(unsigned short s) {
    union { unsigned u; float f; } v;
    v.u = ((unsigned)s) << 16;
    return v.f;
}
__device__ __forceinline__ unsigned short f2bf(float f) {
    union { float f; unsigned u; } v;
    v.f = f;
    unsigned r = (v.u + 0x7FFFu + ((v.u >> 16) & 1u)) >> 16;
    return (unsigned short)r;
}

// ---------------------------- CSR build ------------------------------------

__global__ void count_kernel(const int* __restrict__ dst, int E, int* __restrict__ cnt) {
    int e = blockIdx.x * blockDim.x + threadIdx.x;
    if (e < E) atomicAdd(&cnt[dst[e]], 1);
}

__global__ void dinv_kernel(const int* __restrict__ cnt, float* __restrict__ dinv, int n) {
    int i = blockIdx.x * blockDim.x + threadIdx.x;
    if (i < n) dinv[i] = rsqrtf((float)cnt[i] + 1.0f);  // deg = in-degree + self loop
}

__global__ void scan_kernel(const int* __restrict__ cnt, int n, int* __restrict__ row_ptr) {
    __shared__ int wsum[16];
    __shared__ int s_base;
    int tid = threadIdx.x;
    int lane = tid & 63;
    int w = tid >> 6;
    if (tid == 0) s_base = 0;
    __syncthreads();
    for (int start = 0; start < n; start += 1024) {
        int i = start + tid;
        int v = (i < n) ? cnt[i] : 0;
        int incl = v;
        #pragma unroll
        for (int off = 1; off < 64; off <<= 1) {
            int t = __shfl_up(incl, off);
            if (lane >= off) incl += t;
        }
        if (lane == 63) wsum[w] = incl;
        __syncthreads();
        int woff = 0;
        for (int j = 0; j < w; j++) woff += wsum[j];
        int excl = s_base + woff + incl - v;
        if (i < n) row_ptr[i] = excl;
        __syncthreads();
        if (tid == 1023) s_base = excl + v;
        __syncthreads();
    }
    if (threadIdx.x == 0) row_ptr[n] = s_base;
}

__global__ void scatter_kernel(const int* __restrict__ src, const int* __restrict__ dst, int E,
                               const int* __restrict__ row_ptr, int* __restrict__ fill,
                               const float* __restrict__ dinv, int* __restrict__ csr_src,
                               float* __restrict__ csr_coef) {
    int e = blockIdx.x * blockDim.x + threadIdx.x;
    if (e < E) {
        int d = dst[e], s = src[e];
        int pos = atomicAdd(&fill[d], 1);
        int idx = row_ptr[d] + pos;
        csr_src[idx] = s;
        csr_coef[idx] = dinv[s] * dinv[d];
    }
}

// ---------------------------- conversions ----------------------------------

__global__ void convert_bf16_vec(const float* __restrict__ in, unsigned short* __restrict__ out, int n4) {
    int i = blockIdx.x * blockDim.x + threadIdx.x;
    if (i < n4) {
        float4 v = ((const float4*)in)[i];
        ushort4 o;
        o.x = f2bf(v.x); o.y = f2bf(v.y); o.z = f2bf(v.z); o.w = f2bf(v.w);
        ((ushort4*)out)[i] = o;
    }
}

// W [K,N] fp32 -> Wt [N,K] bf16
__global__ void convert_wt(const float* __restrict__ W, unsigned short* __restrict__ Wt, int K, int N) {
    int idx = blockIdx.x * blockDim.x + threadIdx.x;
    if (idx < K * N) {
        int k = idx / N, n = idx - k * N;
        Wt[(size_t)n * K + k] = f2bf(W[idx]);
    }
}

// ---------------------------- aggregation ----------------------------------
// s[node] = sum_e coef * h[src_e]  +  dinv^2 * h[node]         (pure, bf16 io)
// One wave per node. Edge (src,coef) prefetched lane-parallel, broadcast via
// __shfl, gathers 4x unrolled -> independent loads in flight.

__launch_bounds__(256)
__global__ void aggregate256(const unsigned short* __restrict__ h,
                             const int* __restrict__ row_ptr,
                             const int* __restrict__ csr_src,
                             const float* __restrict__ csr_coef,
                             const float* __restrict__ dinv,
                             unsigned short* __restrict__ out, int n) {
    int node = blockIdx.x * 4 + (threadIdx.x >> 6);
    int lane = threadIdx.x & 63;
    if (node >= n) return;
    float di = dinv[node];
    float self = di * di;
    ushort4 sv = *(const ushort4*)(h + (size_t)node * 256 + lane * 4);
    float ax = self * bf2f(sv.x), ay = self * bf2f(sv.y);
    float az = self * bf2f(sv.z), aw = self * bf2f(sv.w);
    int beg = row_ptr[node], end = row_ptr[node + 1];
    for (int base = beg; base < end; base += 64) {
        int k = base + lane;
        int mi = 0; float mc = 0.f;
        if (k < end) { mi = csr_src[k]; mc = csr_coef[k]; }
        int cnt = min(64, end - base);
        int j = 0;
        for (; j + 4 <= cnt; j += 4) {
            int s0 = __shfl(mi, j + 0); float c0 = __shfl(mc, j + 0);
            int s1 = __shfl(mi, j + 1); float c1 = __shfl(mc, j + 1);
            int s2 = __shfl(mi, j + 2); float c2 = __shfl(mc, j + 2);
            int s3 = __shfl(mi, j + 3); float c3 = __shfl(mc, j + 3);
            ushort4 v0 = *(const ushort4*)(h + (size_t)s0 * 256 + lane * 4);
            ushort4 v1 = *(const ushort4*)(h + (size_t)s1 * 256 + lane * 4);
            ushort4 v2 = *(const ushort4*)(h + (size_t)s2 * 256 + lane * 4);
            ushort4 v3 = *(const ushort4*)(h + (size_t)s3 * 256 + lane * 4);
            ax += c0 * bf2f(v0.x) + c1 * bf2f(v1.x) + c2 * bf2f(v2.x) + c3 * bf2f(v3.x);
            ay += c0 * bf2f(v0.y) + c1 * bf2f(v1.y) + c2 * bf2f(v2.y) + c3 * bf2f(v3.y);
            az += c0 * bf2f(v0.z) + c1 * bf2f(v1.z) + c2 * bf2f(v2.z) + c3 * bf2f(v3.z);
            aw += c0 * bf2f(v0.w) + c1 * bf2f(v1.w) + c2 * bf2f(v2.w) + c3 * bf2f(v3.w);
        }
        for (; j < cnt; j++) {
            int s = __shfl(mi, j); float c = __shfl(mc, j);
            ushort4 v = *(const ushort4*)(h + (size_t)s * 256 + lane * 4);
            ax += c * bf2f(v.x); ay += c * bf2f(v.y);
            az += c * bf2f(v.z); aw += c * bf2f(v.w);
        }
    }
    ushort4 o;
    o.x = f2bf(ax); o.y = f2bf(ay); o.z = f2bf(az); o.w = f2bf(aw);
    *(ushort4*)(out + (size_t)node * 256 + lane * 4) = o;
}

__launch_bounds__(256)
__global__ void aggregate128(const unsigned short* __restrict__ h,
                             const int* __restrict__ row_ptr,
                             const int* __restrict__ csr_src,
                             const float* __restrict__ csr_coef,
                             const float* __restrict__ dinv,
                             unsigned short* __restrict__ out, int n) {
    int node = blockIdx.x * 4 + (threadIdx.x >> 6);
    int lane = threadIdx.x & 63;
    if (node >= n) return;
    float di = dinv[node];
    float self = di * di;
    ushort2 sv = *(const ushort2*)(h + (size_t)node * 128 + lane * 2);
    float ax = self * bf2f(sv.x), ay = self * bf2f(sv.y);
    int beg = row_ptr[node], end = row_ptr[node + 1];
    for (int base = beg; base < end; base += 64) {
        int k = base + lane;
        int mi = 0; float mc = 0.f;
        if (k < end) { mi = csr_src[k]; mc = csr_coef[k]; }
        int cnt = min(64, end - base);
        int j = 0;
        for (; j + 4 <= cnt; j += 4) {
            int s0 = __shfl(mi, j + 0); float c0 = __shfl(mc, j + 0);
            int s1 = __shfl(mi, j + 1); float c1 = __shfl(mc, j + 1);
            int s2 = __shfl(mi, j + 2); float c2 = __shfl(mc, j + 2);
            int s3 = __shfl(mi, j + 3); float c3 = __shfl(mc, j + 3);
            ushort2 v0 = *(const ushort2*)(h + (size_t)s0 * 128 + lane * 2);
            ushort2 v1 = *(const ushort2*)(h + (size_t)s1 * 128 + lane * 2);
            ushort2 v2 = *(const ushort2*)(h + (size_t)s2 * 128 + lane * 2);
            ushort2 v3 = *(const ushort2*)(h + (size_t)s3 * 128 + lane * 2);
            ax += c0 * bf2f(v0.x) + c1 * bf2f(v1.x) + c2 * bf2f(v2.x) + c3 * bf2f(v3.x);
            ay += c0 * bf2f(v0.y) + c1 * bf2f(v1.y) + c2 * bf2f(v2.y) + c3 * bf2f(v3.y);
        }
        for (; j < cnt; j++) {
            int s = __shfl(mi, j); float c = __shfl(mc, j);
            ushort2 v = *(const ushort2*)(h + (size_t)s * 128 + lane * 2);
            ax += c * bf2f(v.x); ay += c * bf2f(v.y);
        }
    }
    ushort2 o;
    o.x = f2bf(ax); o.y = f2bf(ay);
    *(ushort2*)(out + (size_t)node * 128 + lane * 2) = o;
}

// ---------------------------- bf16 MFMA GEMM -------------------------------
// C[M,N] = relu(A[M,K] @ Bt[N,K]^T + bias) (+ residual), bf16 io, fp32 acc.
// 128x128 tile, BK=32, 4 waves 2x2; each wave 64x64 via 4x4 16x16x32 frags.
#define LDA 40  // padded LDS row stride in shorts (32 + 8)

__launch_bounds__(256)
__global__ void mfma_gemm(const unsigned short* __restrict__ A,
                          const unsigned short* __restrict__ Bt,
                          const float* __restrict__ bias,
                          const unsigned short* __restrict__ residual,
                          unsigned short* __restrict__ C,
                          int M, int N, int K, int relu) {
    __shared__ unsigned short As[128 * LDA];
    __shared__ unsigned short Bs[128 * LDA];
    int tid = threadIdx.x;
    int wave = tid >> 6, lane = tid & 63;
    int wm = wave >> 1, wn = wave & 1;
    int q = lane >> 4, r = lane & 15;
    int bm = blockIdx.y * 128, bn = blockIdx.x * 128;

    f32x4 acc[4][4];
    #pragma unroll
    for (int i = 0; i < 4; i++)
        #pragma unroll
        for (int j = 0; j < 4; j++) acc[i][j] = (f32x4){0.f, 0.f, 0.f, 0.f};

    for (int kt = 0; kt < K; kt += 32) {
        #pragma unroll
        for (int c = 0; c < 2; c++) {
            int f = tid * 2 + c;          // 0..511: 128 rows x 4 chunks of 8 shorts
            int row = f >> 2, kq = f & 3;
            int grow = bm + row;
            short8 va = {0, 0, 0, 0, 0, 0, 0, 0};
            if (grow < M) va = *(const short8*)(A + (size_t)grow * K + kt + kq * 8);
            *(short8*)&As[row * LDA + kq * 8] = va;
            int nrow = bn + row;
            short8 vb = {0, 0, 0, 0, 0, 0, 0, 0};
            if (nrow < N) vb = *(const short8*)(Bt + (size_t)nrow * K + kt + kq * 8);
            *(short8*)&Bs[row * LDA + kq * 8] = vb;
        }
        __syncthreads();
        short8 af[4], bf[4];
        #pragma unroll
        for (int i = 0; i < 4; i++)
            af[i] = *(short8*)&As[(wm * 64 + i * 16 + r) * LDA + q * 8];
        #pragma unroll
        for (int j = 0; j < 4; j++)
            bf[j] = *(short8*)&Bs[(wn * 64 + j * 16 + r) * LDA + q * 8];
        #pragma unroll
        for (int i = 0; i < 4; i++)
            #pragma unroll
            for (int j = 0; j < 4; j++)
                acc[i][j] = __builtin_amdgcn_mfma_f32_16x16x32_bf16(af[i], bf[j], acc[i][j], 0, 0, 0);
        __syncthreads();
    }

    #pragma unroll
    for (int i = 0; i < 4; i++) {
        #pragma unroll
        for (int p = 0; p < 4; p++) {
            int row = bm + wm * 64 + i * 16 + q * 4 + p;
            if (row < M) {
                #pragma unroll
                for (int j = 0; j < 4; j++) {
                    int col = bn + wn * 64 + j * 16 + r;
                    float v = acc[i][j][p];
                    if (bias) v += bias[col];
                    if (relu) v = fmaxf(v, 0.f);
                    if (residual) v += bf2f(residual[(size_t)row * N + col]);
                    C[(size_t)row * N + col] = f2bf(v);
                }
            }
        }
    }
}

// ---------------------------- pool / MLP / LN ------------------------------

__global__ void pool_kernel(const unsigned short* __restrict__ h, const int* __restrict__ batch,
                            float* __restrict__ g0, int n) {
    int g = blockIdx.x;
    __shared__ int s_lo, s_hi;
    if (threadIdx.x == 0) {
        int lo = 0, hi = n;
        while (lo < hi) { int mid = (lo + hi) >> 1; if (batch[mid] < g) lo = mid + 1; else hi = mid; }
        s_lo = lo;
        int lo2 = lo, hi2 = n;
        while (lo2 < hi2) { int mid = (lo2 + hi2) >> 1; if (batch[mid] < g + 1) lo2 = mid + 1; else hi2 = mid; }
        s_hi = lo2;
    }
    __syncthreads();
    int lo = s_lo, hi = s_hi;
    float acc = 0.f;
    for (int i = lo; i < hi; i++) acc += bf2f(h[(size_t)i * 256 + threadIdx.x]);
    float cntf = (float)(hi - lo);
    g0[(size_t)g * 256 + threadIdx.x] = acc / fmaxf(cntf, 1.0f);
}

// fp32 tiled GEMM for the small MLP (M=1024).
__launch_bounds__(256)
__global__ void gemm_kernel(const float* __restrict__ A, const float* __restrict__ B,
                            const float* __restrict__ bias, float* __restrict__ C,
                            int M, int N, int K, int relu) {
    __shared__ float As[16][128];
    __shared__ float Bs[16][128];
    int tid = threadIdx.x;
    int tx = tid & 15, ty = tid >> 4;
    int bm = blockIdx.y * 128, bn = blockIdx.x * 128;

    float acc[8][8];
    #pragma unroll
    for (int i = 0; i < 8; i++)
        #pragma unroll
        for (int j = 0; j < 8; j++) acc[i][j] = 0.f;

    for (int kt = 0; kt < K; kt += 16) {
        #pragma unroll
        for (int t = 0; t < 2; t++) {
            int f = tid * 2 + t;
            int m = f >> 2;
            int kq = f & 3;
            int row = bm + m;
            float4 av = make_float4(0.f, 0.f, 0.f, 0.f);
            if (row < M) av = *(const float4*)(A + (size_t)row * K + kt + kq * 4);
            As[kq * 4 + 0][m] = av.x;
            As[kq * 4 + 1][m] = av.y;
            As[kq * 4 + 2][m] = av.z;
            As[kq * 4 + 3][m] = av.w;
        }
        #pragma unroll
        for (int t = 0; t < 2; t++) {
            int f = tid * 2 + t;
            int k = f >> 5;
            int nq = f & 31;
            float4 bv = *(const float4*)(B + (size_t)(kt + k) * N + bn + nq * 4);
            *(float4*)&Bs[k][nq * 4] = bv;
        }
        __syncthreads();
        #pragma unroll
        for (int kk = 0; kk < 16; kk++) {
            float a[8], b[8];
            *(float4*)&a[0] = *(const float4*)&As[kk][ty * 8];
            *(float4*)&a[4] = *(const float4*)&As[kk][ty * 8 + 4];
            *(float4*)&b[0] = *(const float4*)&Bs[kk][tx * 8];
            *(float4*)&b[4] = *(const float4*)&Bs[kk][tx * 8 + 4];
            #pragma unroll
            for (int i = 0; i < 8; i++)
                #pragma unroll
                for (int j = 0; j < 8; j++) acc[i][j] += a[i] * b[j];
        }
        __syncthreads();
    }

    #pragma unroll
    for (int i = 0; i < 8; i++) {
        int row = bm + ty * 8 + i;
        if (row < M) {
            float o[8];
            #pragma unroll
            for (int j = 0; j < 8; j++) {
                float v = acc[i][j];
                if (bias) v += bias[bn + tx * 8 + j];
                if (relu) v = fmaxf(v, 0.f);
                o[j] = v;
            }
            *(float4*)(C + (size_t)row * N + bn + tx * 8) = *(float4*)&o[0];
            *(float4*)(C + (size_t)row * N + bn + tx * 8 + 4) = *(float4*)&o[4];
        }
    }
}

__launch_bounds__(256)
__global__ void ln_kernel(const float* __restrict__ g2, const float* __restrict__ gamma,
                          const float* __restrict__ beta, float* __restrict__ out, int rows) {
    int row = blockIdx.x * 4 + (threadIdx.x >> 6);
    int lane = threadIdx.x & 63;
    if (row >= rows) return;
    const float* r = g2 + (size_t)row * 768;
    float v[12];
    float s = 0.f, s2 = 0.f;
    #pragma unroll
    for (int j = 0; j < 12; j++) {
        v[j] = r[lane + 64 * j];
        s += v[j];
        s2 += v[j] * v[j];
    }
    #pragma unroll
    for (int off = 32; off > 0; off >>= 1) {
        s += __shfl_down(s, off);
        s2 += __shfl_down(s2, off);
    }
    s = __shfl(s, 0);
    s2 = __shfl(s2, 0);
    float mu = s * (1.0f / 768.0f);
    float var = s2 * (1.0f / 768.0f) - mu * mu;
    float inv = rsqrtf(var + 1e-5f);
    #pragma unroll
    for (int j = 0; j < 12; j++) {
        int c = lane + 64 * j;
        out[(size_t)row * 768 + c] = (v[j] - mu) * inv * gamma[c] + beta[c];
    }
}

// ---------------------------------------------------------------------------

extern "C" void kernel_launch(void* const* d_in, const int* in_sizes, int n_in,
                              void* d_out, int out_size, void* d_ws, size_t ws_size,
                              hipStream_t stream) {
    const float* x    = (const float*)d_in[0];
    const int* eidx   = (const int*)d_in[1];
    const int* batch  = (const int*)d_in[2];
    const float* W1   = (const float*)d_in[3];
    const float* b1   = (const float*)d_in[4];
    const float* W2   = (const float*)d_in[5];
    const float* b2   = (const float*)d_in[6];
    const float* W3   = (const float*)d_in[7];
    const float* b3   = (const float*)d_in[8];
    const float* P1   = (const float*)d_in[9];
    const float* pb1  = (const float*)d_in[10];
    const float* P2   = (const float*)d_in[11];
    const float* pb2  = (const float*)d_in[12];
    const float* ln_g = (const float*)d_in[13];
    const float* ln_b = (const float*)d_in[14];
    float* out = (float*)d_out;

    const int N = in_sizes[2];            // 50000
    const int E = in_sizes[1] / 2;        // 800000
    const int F_IN = in_sizes[0] / N;     // 128
    const int H = in_sizes[4];            // 256
    const int D = in_sizes[12];           // 768
    const int G = out_size / D;           // 1024
    const int NPAD = (N + 127) & ~127;

    const int* src = eidx;
    const int* dst = eidx + E;

    char* ws = (char*)d_ws;
    size_t off = 0;
    auto alloc = [&](size_t bytes) -> char* {
        char* p = ws + off;
        off = (off + bytes + 255) & ~(size_t)255;
        return p;
    };
    int*   cnt      = (int*)alloc((size_t)NPAD * 4);   // cnt & fill contiguous -> one memset
    int*   fill     = (int*)alloc((size_t)NPAD * 4);
    float* dinv     = (float*)alloc((size_t)NPAD * 4);
    int*   row_ptr  = (int*)alloc((size_t)(N + 1) * 4);
    int*   csr_src  = (int*)alloc((size_t)E * 4);
    float* csr_coef = (float*)alloc((size_t)E * 4);
    unsigned short* x_bf = (unsigned short*)alloc((size_t)N * F_IN * 2);
    unsigned short* Wt1  = (unsigned short*)alloc((size_t)F_IN * H * 2);
    unsigned short* Wt2  = (unsigned short*)alloc((size_t)H * H * 2);
    unsigned short* Wt3  = (unsigned short*)alloc((size_t)H * H * 2);
    unsigned short* s1   = (unsigned short*)alloc((size_t)N * F_IN * 2);  // Â x (128)
    unsigned short* sA   = (unsigned short*)alloc((size_t)N * H * 2);     // Â h (256)
    unsigned short* h1   = (unsigned short*)alloc((size_t)N * H * 2);
    unsigned short* h2   = (unsigned short*)alloc((size_t)N * H * 2);
    unsigned short* h3   = (unsigned short*)alloc((size_t)N * H * 2);
    float* g0 = (float*)alloc((size_t)G * H * 4);
    float* g1 = (float*)alloc((size_t)G * H * 4);
    float* g2 = (float*)alloc((size_t)G * D * 4);
    (void)ws_size; (void)n_in;

    // --- CSR build -----------------------------------------------------------
    hipMemsetAsync(cnt, 0, (size_t)2 * NPAD * 4, stream);
    count_kernel<<<(E + 255) / 256, 256, 0, stream>>>(dst, E, cnt);
    dinv_kernel<<<(N + 255) / 256, 256, 0, stream>>>(cnt, dinv, N);
    scan_kernel<<<1, 1024, 0, stream>>>(cnt, N, row_ptr);
    scatter_kernel<<<(E + 255) / 256, 256, 0, stream>>>(src, dst, E, row_ptr, fill, dinv,
                                                        csr_src, csr_coef);

    // --- conversions ---------------------------------------------------------
    convert_bf16_vec<<<(N * F_IN / 4 + 255) / 256, 256, 0, stream>>>(x, x_bf, N * F_IN / 4);
    convert_wt<<<(F_IN * H + 255) / 256, 256, 0, stream>>>(W1, Wt1, F_IN, H);
    convert_wt<<<(H * H + 255) / 256, 256, 0, stream>>>(W2, Wt2, H, H);
    convert_wt<<<(H * H + 255) / 256, 256, 0, stream>>>(W3, Wt3, H, H);

    // --- GCN layers (aggregate-first) ---------------------------------------
    int agg_grid = (N + 3) / 4;
    dim3 ggrid(H / 128, (N + 127) / 128);

    // layer 1: s1 = Â x (128-dim), h1 = relu(s1 @ W1 + b1)
    aggregate128<<<agg_grid, 256, 0, stream>>>(x_bf, row_ptr, csr_src, csr_coef, dinv, s1, N);
    mfma_gemm<<<ggrid, 256, 0, stream>>>(s1, Wt1, b1, nullptr, h1, N, H, F_IN, 1);

    // layer 2: sA = Â h1, h2 = relu(sA @ W2 + b2) + h1
    aggregate256<<<agg_grid, 256, 0, stream>>>(h1, row_ptr, csr_src, csr_coef, dinv, sA, N);
    mfma_gemm<<<ggrid, 256, 0, stream>>>(sA, Wt2, b2, h1, h2, N, H, H, 1);

    // layer 3: sA = Â h2, h3 = relu(sA @ W3 + b3) + h2
    aggregate256<<<agg_grid, 256, 0, stream>>>(h2, row_ptr, csr_src, csr_coef, dinv, sA, N);
    mfma_gemm<<<ggrid, 256, 0, stream>>>(sA, Wt3, b3, h2, h3, N, H, H, 1);

    // --- pool + MLP + LN -----------------------------------------------------
    pool_kernel<<<G, 256, 0, stream>>>(h3, batch, g0, N);
    dim3 p1_grid(H / 128, (G + 127) / 128);
    gemm_kernel<<<p1_grid, 256, 0, stream>>>(g0, P1, pb1, g1, G, H, H, 1);
    dim3 p2_grid(D / 128, (G + 127) / 128);
    gemm_kernel<<<p2_grid, 256, 0, stream>>>(g1, P2, pb2, g2, G, D, H, 0);
    ln_kernel<<<G / 4, 256, 0, stream>>>(g2, ln_g, ln_b, out, G);
}

// Round 4
// 489.188 us; speedup vs baseline: 2.0266x; 1.3872x over previous
//
#include <hip/hip_runtime.h>

// ---------------------------------------------------------------------------
// GraphEncoder round 4:
//  - wgemm: weight-stationary MFMA GEMM for skinny K (128/256).
//    B strip (64 cols x K) staged to LDS ONCE (one barrier); A fragments
//    loaded straight from global into VGPRs (issued before the barrier).
//    Zero barriers in the K loop -> kills the 73us latency-bound m97-style
//    loop (8 K-iters x 2 barriers was structurally latency-bound).
//  - Same kernel runs the MLP (P1 relu bf16, P2 -> fp32 for LN).
//  - aggregator: 8-wide independent-gather unroll.
//  - scan: 4 elems/thread.
// ---------------------------------------------------------------------------

typedef __attribute__((ext_vector_type(8))) short short8;
typedef __attribute__((ext_vector_type(4))) float f32x4;

__device__ __forceinline__ float bf2f(unsigned short s) {
    union { unsigned u; float f; } v;
    v.u = ((unsigned)s) << 16;
    return v.f;
}
__device__ __forceinline__ unsigned short f2bf(float f) {
    union { float f; unsigned u; } v;
    v.f = f;
    unsigned r = (v.u + 0x7FFFu + ((v.u >> 16) & 1u)) >> 16;
    return (unsigned short)r;
}

// ---------------------------- CSR build ------------------------------------

__global__ void count_kernel(const int* __restrict__ dst, int E, int* __restrict__ cnt) {
    int e = blockIdx.x * blockDim.x + threadIdx.x;
    if (e < E) atomicAdd(&cnt[dst[e]], 1);
}

__global__ void dinv_kernel(const int* __restrict__ cnt, float* __restrict__ dinv, int n) {
    int i = blockIdx.x * blockDim.x + threadIdx.x;
    if (i < n) dinv[i] = rsqrtf((float)cnt[i] + 1.0f);  // deg = in-degree + self loop
}

// Exclusive scan, 4 elems/thread, single 1024-thread block (4096/pass).
__global__ void scan_kernel(const int* __restrict__ cnt, int n, int* __restrict__ row_ptr) {
    __shared__ int wsum[16];
    __shared__ int s_base;
    int tid = threadIdx.x;
    int lane = tid & 63;
    int w = tid >> 6;
    if (tid == 0) s_base = 0;
    __syncthreads();
    for (int start = 0; start < n; start += 4096) {
        int i = start + tid * 4;
        int v0 = (i + 0 < n) ? cnt[i + 0] : 0;
        int v1 = (i + 1 < n) ? cnt[i + 1] : 0;
        int v2 = (i + 2 < n) ? cnt[i + 2] : 0;
        int v3 = (i + 3 < n) ? cnt[i + 3] : 0;
        int s = v0 + v1 + v2 + v3;
        int incl = s;
        #pragma unroll
        for (int off = 1; off < 64; off <<= 1) {
            int t = __shfl_up(incl, off);
            if (lane >= off) incl += t;
        }
        if (lane == 63) wsum[w] = incl;
        __syncthreads();
        int woff = 0;
        for (int j = 0; j < w; j++) woff += wsum[j];
        int excl = s_base + woff + incl - s;
        if (i + 0 < n) row_ptr[i + 0] = excl;
        if (i + 1 < n) row_ptr[i + 1] = excl + v0;
        if (i + 2 < n) row_ptr[i + 2] = excl + v0 + v1;
        if (i + 3 < n) row_ptr[i + 3] = excl + v0 + v1 + v2;
        __syncthreads();
        if (tid == 1023) s_base = excl + s;
        __syncthreads();
    }
    if (threadIdx.x == 0) row_ptr[n] = s_base;
}

__global__ void scatter_kernel(const int* __restrict__ src, const int* __restrict__ dst, int E,
                               const int* __restrict__ row_ptr, int* __restrict__ fill,
                               const float* __restrict__ dinv, int* __restrict__ csr_src,
                               float* __restrict__ csr_coef) {
    int e = blockIdx.x * blockDim.x + threadIdx.x;
    if (e < E) {
        int d = dst[e], s = src[e];
        int pos = atomicAdd(&fill[d], 1);
        int idx = row_ptr[d] + pos;
        csr_src[idx] = s;
        csr_coef[idx] = dinv[s] * dinv[d];
    }
}

// ---------------------------- conversions ----------------------------------

__global__ void convert_bf16_vec(const float* __restrict__ in, unsigned short* __restrict__ out, int n4) {
    int i = blockIdx.x * blockDim.x + threadIdx.x;
    if (i < n4) {
        float4 v = ((const float4*)in)[i];
        ushort4 o;
        o.x = f2bf(v.x); o.y = f2bf(v.y); o.z = f2bf(v.z); o.w = f2bf(v.w);
        ((ushort4*)out)[i] = o;
    }
}

// W [K,N] fp32 -> Wt [N,K] bf16
__global__ void convert_wt(const float* __restrict__ W, unsigned short* __restrict__ Wt, int K, int N) {
    int idx = blockIdx.x * blockDim.x + threadIdx.x;
    if (idx < K * N) {
        int k = idx / N, n = idx - k * N;
        Wt[(size_t)n * K + k] = f2bf(W[idx]);
    }
}

// ---------------------------- aggregation ----------------------------------
// s[node] = sum_e coef * h[src_e] + dinv^2 * h[node]   (pure, bf16 io)
// One wave per node; edge (src,coef) prefetched lane-parallel, broadcast via
// __shfl; gathers 8x unrolled -> 8 independent loads in flight per wave.

__launch_bounds__(256)
__global__ void aggregate256(const unsigned short* __restrict__ h,
                             const int* __restrict__ row_ptr,
                             const int* __restrict__ csr_src,
                             const float* __restrict__ csr_coef,
                             const float* __restrict__ dinv,
                             unsigned short* __restrict__ out, int n) {
    int node = blockIdx.x * 4 + (threadIdx.x >> 6);
    int lane = threadIdx.x & 63;
    if (node >= n) return;
    float di = dinv[node];
    float self = di * di;
    ushort4 sv = *(const ushort4*)(h + (size_t)node * 256 + lane * 4);
    float ax = self * bf2f(sv.x), ay = self * bf2f(sv.y);
    float az = self * bf2f(sv.z), aw = self * bf2f(sv.w);
    int beg = row_ptr[node], end = row_ptr[node + 1];
    for (int base = beg; base < end; base += 64) {
        int k = base + lane;
        int mi = 0; float mc = 0.f;
        if (k < end) { mi = csr_src[k]; mc = csr_coef[k]; }
        int cnt = min(64, end - base);
        int j = 0;
        for (; j + 8 <= cnt; j += 8) {
            int ss[8]; float cc[8]; ushort4 vv[8];
            #pragma unroll
            for (int u = 0; u < 8; u++) { ss[u] = __shfl(mi, j + u); cc[u] = __shfl(mc, j + u); }
            #pragma unroll
            for (int u = 0; u < 8; u++) vv[u] = *(const ushort4*)(h + (size_t)ss[u] * 256 + lane * 4);
            #pragma unroll
            for (int u = 0; u < 8; u++) {
                ax += cc[u] * bf2f(vv[u].x); ay += cc[u] * bf2f(vv[u].y);
                az += cc[u] * bf2f(vv[u].z); aw += cc[u] * bf2f(vv[u].w);
            }
        }
        for (; j < cnt; j++) {
            int s = __shfl(mi, j); float c = __shfl(mc, j);
            ushort4 v = *(const ushort4*)(h + (size_t)s * 256 + lane * 4);
            ax += c * bf2f(v.x); ay += c * bf2f(v.y);
            az += c * bf2f(v.z); aw += c * bf2f(v.w);
        }
    }
    ushort4 o;
    o.x = f2bf(ax); o.y = f2bf(ay); o.z = f2bf(az); o.w = f2bf(aw);
    *(ushort4*)(out + (size_t)node * 256 + lane * 4) = o;
}

__launch_bounds__(256)
__global__ void aggregate128(const unsigned short* __restrict__ h,
                             const int* __restrict__ row_ptr,
                             const int* __restrict__ csr_src,
                             const float* __restrict__ csr_coef,
                             const float* __restrict__ dinv,
                             unsigned short* __restrict__ out, int n) {
    int node = blockIdx.x * 4 + (threadIdx.x >> 6);
    int lane = threadIdx.x & 63;
    if (node >= n) return;
    float di = dinv[node];
    float self = di * di;
    ushort2 sv = *(const ushort2*)(h + (size_t)node * 128 + lane * 2);
    float ax = self * bf2f(sv.x), ay = self * bf2f(sv.y);
    int beg = row_ptr[node], end = row_ptr[node + 1];
    for (int base = beg; base < end; base += 64) {
        int k = base + lane;
        int mi = 0; float mc = 0.f;
        if (k < end) { mi = csr_src[k]; mc = csr_coef[k]; }
        int cnt = min(64, end - base);
        int j = 0;
        for (; j + 8 <= cnt; j += 8) {
            int ss[8]; float cc[8]; ushort2 vv[8];
            #pragma unroll
            for (int u = 0; u < 8; u++) { ss[u] = __shfl(mi, j + u); cc[u] = __shfl(mc, j + u); }
            #pragma unroll
            for (int u = 0; u < 8; u++) vv[u] = *(const ushort2*)(h + (size_t)ss[u] * 128 + lane * 2);
            #pragma unroll
            for (int u = 0; u < 8; u++) {
                ax += cc[u] * bf2f(vv[u].x); ay += cc[u] * bf2f(vv[u].y);
            }
        }
        for (; j < cnt; j++) {
            int s = __shfl(mi, j); float c = __shfl(mc, j);
            ushort2 v = *(const ushort2*)(h + (size_t)s * 128 + lane * 2);
            ax += c * bf2f(v.x); ay += c * bf2f(v.y);
        }
    }
    ushort2 o;
    o.x = f2bf(ax); o.y = f2bf(ay);
    *(ushort2*)(out + (size_t)node * 128 + lane * 2) = o;
}

// ---------------------------- weight-stationary GEMM -----------------------
// C[M,N] = act(A[M,K] @ Bt[N,K]^T + bias) [+ residual]
// Block: 4 waves, 128 M-rows x 64 N-cols. B strip in LDS (one barrier);
// A frags direct global->VGPR issued BEFORE the barrier; no K-loop barriers.
// LDS row stride K+8 shorts -> b128 frag reads at the 8-cycle floor.

template<int K, int RELU, int RES, int OUTF32>
__launch_bounds__(256)
__global__ void wgemm(const unsigned short* __restrict__ A,
                      const unsigned short* __restrict__ Bt,
                      const float* __restrict__ bias,
                      const unsigned short* __restrict__ residual,
                      void* __restrict__ Cout,
                      int M, int N) {
    constexpr int S = K + 8;        // LDS stride (shorts)
    constexpr int KK = K / 32;      // k-steps
    constexpr int CPR = K / 8;      // 16B chunks per B row
    __shared__ unsigned short Bs[64 * S];

    int tid = threadIdx.x;
    int wave = tid >> 6, lane = tid & 63;
    int r = lane & 15, q = lane >> 4;
    int n0 = blockIdx.x * 64;
    int m0 = blockIdx.y * 128;
    int mr = m0 + wave * 32;

    // A fragments: global -> VGPR, issued before staging barrier.
    short8 a[2][KK];
    #pragma unroll
    for (int mi = 0; mi < 2; mi++) {
        int arow = mr + mi * 16 + r;
        bool ok = arow < M;
        const unsigned short* ap = A + (size_t)(ok ? arow : 0) * K;
        #pragma unroll
        for (int kk = 0; kk < KK; kk++) {
            short8 v = *(const short8*)(ap + kk * 32 + q * 8);
            if (!ok) v = (short8){0, 0, 0, 0, 0, 0, 0, 0};
            a[mi][kk] = v;
        }
    }

    // Stage B strip: 64 rows x K shorts.
    #pragma unroll
    for (int pass = 0; pass < 64 * CPR / 256; pass++) {
        int f = pass * 256 + tid;
        int row = f / CPR, ch = f % CPR;
        *(short8*)&Bs[row * S + ch * 8] =
            *(const short8*)(Bt + (size_t)(n0 + row) * K + ch * 8);
    }
    __syncthreads();

    f32x4 acc[2][4];
    #pragma unroll
    for (int mi = 0; mi < 2; mi++)
        #pragma unroll
        for (int j = 0; j < 4; j++) acc[mi][j] = (f32x4){0.f, 0.f, 0.f, 0.f};

    #pragma unroll
    for (int kk = 0; kk < KK; kk++) {
        short8 b[4];
        #pragma unroll
        for (int j = 0; j < 4; j++)
            b[j] = *(short8*)&Bs[(j * 16 + r) * S + kk * 32 + q * 8];
        #pragma unroll
        for (int mi = 0; mi < 2; mi++)
            #pragma unroll
            for (int j = 0; j < 4; j++)
                acc[mi][j] = __builtin_amdgcn_mfma_f32_16x16x32_bf16(a[mi][kk], b[j], acc[mi][j], 0, 0, 0);
    }

    float bb[4];
    #pragma unroll
    for (int j = 0; j < 4; j++) bb[j] = bias[n0 + j * 16 + r];

    #pragma unroll
    for (int mi = 0; mi < 2; mi++) {
        #pragma unroll
        for (int p = 0; p < 4; p++) {
            int row = mr + mi * 16 + q * 4 + p;
            if (row < M) {
                #pragma unroll
                for (int j = 0; j < 4; j++) {
                    int col = n0 + j * 16 + r;
                    float v = acc[mi][j][p] + bb[j];
                    if (RELU) v = fmaxf(v, 0.f);
                    if (RES) v += bf2f(residual[(size_t)row * N + col]);
                    if (OUTF32) ((float*)Cout)[(size_t)row * N + col] = v;
                    else ((unsigned short*)Cout)[(size_t)row * N + col] = f2bf(v);
                }
            }
        }
    }
}

// ---------------------------- pool / LN ------------------------------------

__global__ void pool_kernel(const unsigned short* __restrict__ h, const int* __restrict__ batch,
                            unsigned short* __restrict__ g0, int n) {
    int g = blockIdx.x;
    __shared__ int s_lo, s_hi;
    if (threadIdx.x == 0) {
        int lo = 0, hi = n;
        while (lo < hi) { int mid = (lo + hi) >> 1; if (batch[mid] < g) lo = mid + 1; else hi = mid; }
        s_lo = lo;
        int lo2 = lo, hi2 = n;
        while (lo2 < hi2) { int mid = (lo2 + hi2) >> 1; if (batch[mid] < g + 1) lo2 = mid + 1; else hi2 = mid; }
        s_hi = lo2;
    }
    __syncthreads();
    int lo = s_lo, hi = s_hi;
    float acc = 0.f;
    for (int i = lo; i < hi; i++) acc += bf2f(h[(size_t)i * 256 + threadIdx.x]);
    float cntf = (float)(hi - lo);
    g0[(size_t)g * 256 + threadIdx.x] = f2bf(acc / fmaxf(cntf, 1.0f));
}

__launch_bounds__(256)
__global__ void ln_kernel(const float* __restrict__ g2, const float* __restrict__ gamma,
                          const float* __restrict__ beta, float* __restrict__ out, int rows) {
    int row = blockIdx.x * 4 + (threadIdx.x >> 6);
    int lane = threadIdx.x & 63;
    if (row >= rows) return;
    const float* r = g2 + (size_t)row * 768;
    float v[12];
    float s = 0.f, s2 = 0.f;
    #pragma unroll
    for (int j = 0; j < 12; j++) {
        v[j] = r[lane + 64 * j];
        s += v[j];
        s2 += v[j] * v[j];
    }
    #pragma unroll
    for (int off = 32; off > 0; off >>= 1) {
        s += __shfl_down(s, off);
        s2 += __shfl_down(s2, off);
    }
    s = __shfl(s, 0);
    s2 = __shfl(s2, 0);
    float mu = s * (1.0f / 768.0f);
    float var = s2 * (1.0f / 768.0f) - mu * mu;
    float inv = rsqrtf(var + 1e-5f);
    #pragma unroll
    for (int j = 0; j < 12; j++) {
        int c = lane + 64 * j;
        out[(size_t)row * 768 + c] = (v[j] - mu) * inv * gamma[c] + beta[c];
    }
}

// ---------------------------------------------------------------------------

extern "C" void kernel_launch(void* const* d_in, const int* in_sizes, int n_in,
                              void* d_out, int out_size, void* d_ws, size_t ws_size,
                              hipStream_t stream) {
    const float* x    = (const float*)d_in[0];
    const int* eidx   = (const int*)d_in[1];
    const int* batch  = (const int*)d_in[2];
    const float* W1   = (const float*)d_in[3];
    const float* b1   = (const float*)d_in[4];
    const float* W2   = (const float*)d_in[5];
    const float* b2   = (const float*)d_in[6];
    const float* W3   = (const float*)d_in[7];
    const float* b3   = (const float*)d_in[8];
    const float* P1   = (const float*)d_in[9];
    const float* pb1  = (const float*)d_in[10];
    const float* P2   = (const float*)d_in[11];
    const float* pb2  = (const float*)d_in[12];
    const float* ln_g = (const float*)d_in[13];
    const float* ln_b = (const float*)d_in[14];
    float* out = (float*)d_out;

    const int N = in_sizes[2];            // 50000
    const int E = in_sizes[1] / 2;        // 800000
    const int F_IN = in_sizes[0] / N;     // 128
    const int H = in_sizes[4];            // 256
    const int D = in_sizes[12];           // 768
    const int G = out_size / D;           // 1024
    const int NPAD = (N + 127) & ~127;

    const int* src = eidx;
    const int* dst = eidx + E;

    char* ws = (char*)d_ws;
    size_t off = 0;
    auto alloc = [&](size_t bytes) -> char* {
        char* p = ws + off;
        off = (off + bytes + 255) & ~(size_t)255;
        return p;
    };
    int*   cnt      = (int*)alloc((size_t)NPAD * 4);   // cnt & fill contiguous -> one memset
    int*   fill     = (int*)alloc((size_t)NPAD * 4);
    float* dinv     = (float*)alloc((size_t)NPAD * 4);
    int*   row_ptr  = (int*)alloc((size_t)(N + 1) * 4);
    int*   csr_src  = (int*)alloc((size_t)E * 4);
    float* csr_coef = (float*)alloc((size_t)E * 4);
    unsigned short* x_bf = (unsigned short*)alloc((size_t)N * F_IN * 2);
    unsigned short* Wt1  = (unsigned short*)alloc((size_t)F_IN * H * 2);
    unsigned short* Wt2  = (unsigned short*)alloc((size_t)H * H * 2);
    unsigned short* Wt3  = (unsigned short*)alloc((size_t)H * H * 2);
    unsigned short* Pt1  = (unsigned short*)alloc((size_t)H * H * 2);
    unsigned short* Pt2  = (unsigned short*)alloc((size_t)H * D * 2);
    unsigned short* s1   = (unsigned short*)alloc((size_t)N * F_IN * 2);  // Â x (128)
    unsigned short* sA   = (unsigned short*)alloc((size_t)N * H * 2);     // Â h (256)
    unsigned short* h1   = (unsigned short*)alloc((size_t)N * H * 2);
    unsigned short* h2   = (unsigned short*)alloc((size_t)N * H * 2);
    unsigned short* h3   = (unsigned short*)alloc((size_t)N * H * 2);
    unsigned short* g0b  = (unsigned short*)alloc((size_t)G * H * 2);
    unsigned short* g1b  = (unsigned short*)alloc((size_t)G * H * 2);
    float* g2 = (float*)alloc((size_t)G * D * 4);
    (void)ws_size; (void)n_in;

    // --- CSR build -----------------------------------------------------------
    hipMemsetAsync(cnt, 0, (size_t)2 * NPAD * 4, stream);
    count_kernel<<<(E + 255) / 256, 256, 0, stream>>>(dst, E, cnt);
    dinv_kernel<<<(N + 255) / 256, 256, 0, stream>>>(cnt, dinv, N);
    scan_kernel<<<1, 1024, 0, stream>>>(cnt, N, row_ptr);
    scatter_kernel<<<(E + 255) / 256, 256, 0, stream>>>(src, dst, E, row_ptr, fill, dinv,
                                                        csr_src, csr_coef);

    // --- conversions ---------------------------------------------------------
    convert_bf16_vec<<<(N * F_IN / 4 + 255) / 256, 256, 0, stream>>>(x, x_bf, N * F_IN / 4);
    convert_wt<<<(F_IN * H + 255) / 256, 256, 0, stream>>>(W1, Wt1, F_IN, H);
    convert_wt<<<(H * H + 255) / 256, 256, 0, stream>>>(W2, Wt2, H, H);
    convert_wt<<<(H * H + 255) / 256, 256, 0, stream>>>(W3, Wt3, H, H);
    convert_wt<<<(H * H + 255) / 256, 256, 0, stream>>>(P1, Pt1, H, H);
    convert_wt<<<(H * D + 255) / 256, 256, 0, stream>>>(P2, Pt2, H, D);

    // --- GCN layers (aggregate-first) ---------------------------------------
    int agg_grid = (N + 3) / 4;
    int mtiles = (N + 127) / 128;

    // layer 1: s1 = Â x (128-dim), h1 = relu(s1 @ W1 + b1)
    aggregate128<<<agg_grid, 256, 0, stream>>>(x_bf, row_ptr, csr_src, csr_coef, dinv, s1, N);
    wgemm<128, 1, 0, 0><<<dim3(H / 64, mtiles), 256, 0, stream>>>(s1, Wt1, b1, nullptr, h1, N, H);

    // layer 2: sA = Â h1, h2 = relu(sA @ W2 + b2) + h1
    aggregate256<<<agg_grid, 256, 0, stream>>>(h1, row_ptr, csr_src, csr_coef, dinv, sA, N);
    wgemm<256, 1, 1, 0><<<dim3(H / 64, mtiles), 256, 0, stream>>>(sA, Wt2, b2, h1, h2, N, H);

    // layer 3: sA = Â h2, h3 = relu(sA @ W3 + b3) + h2
    aggregate256<<<agg_grid, 256, 0, stream>>>(h2, row_ptr, csr_src, csr_coef, dinv, sA, N);
    wgemm<256, 1, 1, 0><<<dim3(H / 64, mtiles), 256, 0, stream>>>(sA, Wt3, b3, h2, h3, N, H);

    // --- pool + MLP + LN -----------------------------------------------------
    pool_kernel<<<G, 256, 0, stream>>>(h3, batch, g0b, N);
    wgemm<256, 1, 0, 0><<<dim3(H / 64, G / 128), 256, 0, stream>>>(g0b, Pt1, pb1, nullptr, g1b, G, H);
    wgemm<256, 0, 0, 1><<<dim3(D / 64, G / 128), 256, 0, stream>>>(g1b, Pt2, pb2, nullptr, g2, G, D);
    ln_kernel<<<G / 4, 256, 0, stream>>>(g2, ln_g, ln_b, out, G);
}